// Round 6
// baseline (43.505 us; speedup 1.0000x reference)
//
#include <hip/hip_runtime.h>
#include <math.h>

#define BB 8
#define KK 4
#define CT 524288          // C*T
#define VECS (CT/4)        // 131072 float4 per (b,k)
#define GX 64              // blocks per batch -> 512 blocks total = 2/CU exactly
#define TPB 256
#define NIT 4              // block covers NIT*512 float4 positions
#define NBITS 2048
#define NACC 25            // 16 cross + 4 p2 + 4 t2 + 1 cons

typedef float f32x4 __attribute__((ext_vector_type(4)));

// SGPR-base + VGPR 32-bit byte offset; volatile => issue order pinned.
#define LOADA(dst, voff, base) \
  asm volatile("global_load_dwordx4 %0, %1, %2" : "=&v"(dst) : "v"(voff), "s"(base))
#define LOADB(dst, voff, base) \
  asm volatile("global_load_dwordx4 %0, %1, %2 offset:2048" : "=&v"(dst) : "v"(voff), "s"(base))
#define WAITV(n) do { \
  __builtin_amdgcn_sched_barrier(0); \
  asm volatile("s_waitcnt vmcnt(" #n ")" ::: "memory"); \
  __builtin_amdgcn_sched_barrier(0); } while (0)

// 18 loads for one iteration: group0 -> G0[9] at voff, group1 -> G1[9] at voff+2048B
#define ISSUE(G0, G1, voff) do { \
  LOADA(G0[0], (voff), b_s0); LOADA(G0[1], (voff), b_s1); \
  LOADA(G0[2], (voff), b_s2); LOADA(G0[3], (voff), b_s3); \
  LOADA(G0[4], (voff), b_t0); LOADA(G0[5], (voff), b_t1); \
  LOADA(G0[6], (voff), b_t2); LOADA(G0[7], (voff), b_t3); \
  LOADA(G0[8], (voff), b_mm); \
  LOADB(G1[0], (voff), b_s0); LOADB(G1[1], (voff), b_s1); \
  LOADB(G1[2], (voff), b_s2); LOADB(G1[3], (voff), b_s3); \
  LOADB(G1[4], (voff), b_t0); LOADB(G1[5], (voff), b_t1); \
  LOADB(G1[6], (voff), b_t2); LOADB(G1[7], (voff), b_t3); \
  LOADB(G1[8], (voff), b_mm); \
} while (0)

__global__ __launch_bounds__(TPB, 2) void floss_reduce(
    const float* __restrict__ sep, const float* __restrict__ src,
    const float* __restrict__ mix, float* __restrict__ ws) {
  const int b = blockIdx.y;
  const float* sepb = sep + (size_t)b * KK * CT;
  const float* srcb = src + (size_t)b * KK * CT;
  const float* mixb = mix + (size_t)b * CT;

  // uniform stream bases -> SGPR pairs
  const float* b_s0 = sepb + 0 * (size_t)CT;
  const float* b_s1 = sepb + 1 * (size_t)CT;
  const float* b_s2 = sepb + 2 * (size_t)CT;
  const float* b_s3 = sepb + 3 * (size_t)CT;
  const float* b_t0 = srcb + 0 * (size_t)CT;
  const float* b_t1 = srcb + 1 * (size_t)CT;
  const float* b_t2 = srcb + 2 * (size_t)CT;
  const float* b_t3 = srcb + 3 * (size_t)CT;
  const float* b_mm = mixb;

  const int tid = threadIdx.x;
  // tid<128 covers [0,128)+[128,256); tid>=128 covers [256,384)+[384,512)
  const int lanepos = ((tid & 128) << 1) + (tid & 127);
  const unsigned vb = (unsigned)(blockIdx.x * (NIT * 512) + lanepos) * 16u;

  float cr[4][4] = {};
  float p2[4] = {};
  float t2[4] = {};
  float cons = 0.f;

  auto consume = [&](const f32x4 (&D)[9]) {
    #pragma unroll
    for (int l = 0; l < 4; ++l) {
      #pragma unroll
      for (int i = 0; i < 4; ++i) {
        float si = D[i][l], ti = D[4 + i][l];
        p2[i] += si * si;
        t2[i] += ti * ti;
        #pragma unroll
        for (int j = 0; j < 4; ++j) cr[i][j] += si * D[4 + j][l];
      }
      float sm = D[0][l] + D[1][l] + D[2][l] + D[3][l] - D[8][l];
      cons += sm * sm;
    }
  };

  f32x4 P0[9], P1[9], Q0[9], Q1[9];

  // software pipeline: always >=18 loads in flight until the tail
  ISSUE(P0, P1, vb);               // iter0          (out 18)
  ISSUE(Q0, Q1, vb + 8192u);       // iter1          (out 36)
  WAITV(27); consume(P0);          // iter0 group0
  WAITV(18); consume(P1);          // iter0 group1   (out 18)
  ISSUE(P0, P1, vb + 16384u);      // iter2          (out 36)
  WAITV(27); consume(Q0);          // iter1 group0
  WAITV(18); consume(Q1);          // iter1 group1   (out 18)
  ISSUE(Q0, Q1, vb + 24576u);      // iter3          (out 36)
  WAITV(27); consume(P0);          // iter2 group0
  WAITV(18); consume(P1);          // iter2 group1   (out 18)
  WAITV(9);  consume(Q0);          // iter3 group0
  WAITV(0);  consume(Q1);          // iter3 group1

  float acc[NACC];
  #pragma unroll
  for (int i = 0; i < 4; ++i)
    #pragma unroll
    for (int j = 0; j < 4; ++j) acc[i * 4 + j] = cr[i][j];
  #pragma unroll
  for (int i = 0; i < 4; ++i) { acc[16 + i] = p2[i]; acc[20 + i] = t2[i]; }
  acc[24] = cons;

  // 64-lane wave reduce
  #pragma unroll
  for (int a = 0; a < NACC; ++a) {
    #pragma unroll
    for (int off = 32; off > 0; off >>= 1)
      acc[a] += __shfl_down(acc[a], off);
  }

  __shared__ float redu[4][NACC];
  const int wave = tid >> 6, lane = tid & 63;
  if (lane == 0) {
    #pragma unroll
    for (int a = 0; a < NACC; ++a) redu[wave][a] = acc[a];
  }
  __syncthreads();
  if (tid < NACC) {
    float v = redu[0][tid] + redu[1][tid] + redu[2][tid] + redu[3][tid];
    // transposed: ws[(a*BB + b)*GX + gx] -> contiguous reads in finalize
    ws[((size_t)tid * BB + b) * GX + blockIdx.x] = v;
  }
}

__global__ __launch_bounds__(256) void floss_finalize(
    const float* __restrict__ ws, const float* __restrict__ pred_bits,
    const int* __restrict__ target_bits, const float* __restrict__ flow_loss,
    float* __restrict__ out) {
  __shared__ float sums[BB * NACC];
  const int t = threadIdx.x;

  if (t < BB * NACC) {
    const int a = t >> 3, b = t & 7;
    const float4* p = (const float4*)(ws + ((size_t)a * BB + b) * GX);
    float4 s4 = make_float4(0.f, 0.f, 0.f, 0.f);
    #pragma unroll
    for (int g = 0; g < GX / 4; ++g) {
      float4 x = p[g];
      s4.x += x.x; s4.y += x.y; s4.z += x.z; s4.w += x.w;
    }
    sums[b * NACC + a] = s4.x + s4.y + s4.z + s4.w;
  }

  float acc = 0.f;
  for (int i = t; i < NBITS; i += 256) {
    float tb = (float)target_bits[i];
    float p = pred_bits[i];
    p = fminf(fmaxf(p, 1e-7f), 1.f - 1e-7f);
    acc += tb * logf(p) + (1.f - tb) * logf(1.f - p);
  }
  #pragma unroll
  for (int off = 32; off > 0; off >>= 1) acc += __shfl_down(acc, off);
  __shared__ float sacc[4];
  const int wave = t >> 6, lane = t & 63;
  if (lane == 0) sacc[wave] = acc;
  __syncthreads();

  if (t == 0) {
    float bsum = sacc[0] + sacc[1] + sacc[2] + sacc[3];
    float bce = -bsum / (float)NBITS;
    float bit = bce * 0.5f;

    const float inv_n = 1.f / (float)CT;
    float recon_sum = 0.f;
    float cons_sum = 0.f;
    for (int b = 0; b < BB; ++b) {
      const float* w = sums + b * NACC;
      cons_sum += w[24];
      float cost[4][4];
      for (int i = 0; i < 4; ++i)
        for (int j = 0; j < 4; ++j)
          cost[i][j] = (w[16 + i] + w[20 + j] - 2.f * w[i * 4 + j]) * inv_n;
      bool used[4] = {false, false, false, false};
      for (int i = 0; i < 4; ++i) {
        int bj = 0; float bv = INFINITY;
        for (int j = 0; j < 4; ++j) {
          if (!used[j] && cost[i][j] < bv) { bv = cost[i][j]; bj = j; }
        }
        recon_sum += bv; used[bj] = true;
      }
    }
    float recon = recon_sum / (float)BB * 0.1f;
    float cons = cons_sum / (float)(BB * CT) * 0.1f;
    float flow = flow_loss[0];
    out[0] = flow;
    out[1] = recon;
    out[2] = cons;
    out[3] = bit;
    out[4] = flow + recon + cons + bit;
  }
}

extern "C" void kernel_launch(void* const* d_in, const int* in_sizes, int n_in,
                              void* d_out, int out_size, void* d_ws, size_t ws_size,
                              hipStream_t stream) {
  const float* sep       = (const float*)d_in[0];
  const float* src       = (const float*)d_in[1];
  const float* mix       = (const float*)d_in[2];
  const float* pred_bits = (const float*)d_in[3];
  const float* flow      = (const float*)d_in[4];
  const int*   tgt_bits  = (const int*)d_in[5];
  float* ws = (float*)d_ws;

  floss_reduce<<<dim3(GX, BB), TPB, 0, stream>>>(sep, src, mix, ws);
  floss_finalize<<<1, TPB, 0, stream>>>(ws, pred_bits, tgt_bits, flow, (float*)d_out);
}

// Round 7
// 42.550 us; speedup vs baseline: 1.0224x; 1.0224x over previous
//
#include <hip/hip_runtime.h>
#include <math.h>

#define BB 8
#define KK 4
#define CT 524288          // C*T
#define VECS (CT/4)        // 131072 float4 per (b,k)
#define GX 128             // blocks per batch -> 1024 blocks total = 4/CU
#define TPB 256
#define NIT 2              // block covers NIT*512 float4 positions
#define NBITS 2048
#define NACC 25            // 16 cross + 4 p2 + 4 t2 + 1 cons

typedef float f32x4 __attribute__((ext_vector_type(4)));

// SGPR-base + VGPR 32-bit byte offset; volatile => issue order pinned.
#define LOADA(dst, voff, base) \
  asm volatile("global_load_dwordx4 %0, %1, %2" : "=&v"(dst) : "v"(voff), "s"(base))
#define LOADB(dst, voff, base) \
  asm volatile("global_load_dwordx4 %0, %1, %2 offset:2048" : "=&v"(dst) : "v"(voff), "s"(base))
#define WAITV(n) do { \
  __builtin_amdgcn_sched_barrier(0); \
  asm volatile("s_waitcnt vmcnt(" #n ")" ::: "memory"); \
  __builtin_amdgcn_sched_barrier(0); } while (0)

// 18 loads for one iteration: group0 -> G0[9] at voff, group1 -> G1[9] at voff+2048B
#define ISSUE(G0, G1, voff) do { \
  LOADA(G0[0], (voff), b_s0); LOADA(G0[1], (voff), b_s1); \
  LOADA(G0[2], (voff), b_s2); LOADA(G0[3], (voff), b_s3); \
  LOADA(G0[4], (voff), b_t0); LOADA(G0[5], (voff), b_t1); \
  LOADA(G0[6], (voff), b_t2); LOADA(G0[7], (voff), b_t3); \
  LOADA(G0[8], (voff), b_mm); \
  LOADB(G1[0], (voff), b_s0); LOADB(G1[1], (voff), b_s1); \
  LOADB(G1[2], (voff), b_s2); LOADB(G1[3], (voff), b_s3); \
  LOADB(G1[4], (voff), b_t0); LOADB(G1[5], (voff), b_t1); \
  LOADB(G1[6], (voff), b_t2); LOADB(G1[7], (voff), b_t3); \
  LOADB(G1[8], (voff), b_mm); \
} while (0)

__global__ __launch_bounds__(TPB, 2) void floss_reduce(
    const float* __restrict__ sep, const float* __restrict__ src,
    const float* __restrict__ mix, float* __restrict__ ws) {
  const int b = blockIdx.y;
  const float* sepb = sep + (size_t)b * KK * CT;
  const float* srcb = src + (size_t)b * KK * CT;
  const float* mixb = mix + (size_t)b * CT;

  // uniform stream bases -> SGPR pairs
  const float* b_s0 = sepb + 0 * (size_t)CT;
  const float* b_s1 = sepb + 1 * (size_t)CT;
  const float* b_s2 = sepb + 2 * (size_t)CT;
  const float* b_s3 = sepb + 3 * (size_t)CT;
  const float* b_t0 = srcb + 0 * (size_t)CT;
  const float* b_t1 = srcb + 1 * (size_t)CT;
  const float* b_t2 = srcb + 2 * (size_t)CT;
  const float* b_t3 = srcb + 3 * (size_t)CT;
  const float* b_mm = mixb;

  const int tid = threadIdx.x;
  // tid<128 covers [0,128)+[128,256); tid>=128 covers [256,384)+[384,512)
  const int lanepos = ((tid & 128) << 1) + (tid & 127);
  const unsigned vb = (unsigned)(blockIdx.x * (NIT * 512) + lanepos) * 16u;

  float cr[4][4] = {};
  float p2[4] = {};
  float t2[4] = {};
  float cons = 0.f;

  auto consume = [&](const f32x4 (&D)[9]) {
    #pragma unroll
    for (int l = 0; l < 4; ++l) {
      #pragma unroll
      for (int i = 0; i < 4; ++i) {
        float si = D[i][l], ti = D[4 + i][l];
        p2[i] += si * si;
        t2[i] += ti * ti;
        #pragma unroll
        for (int j = 0; j < 4; ++j) cr[i][j] += si * D[4 + j][l];
      }
      float sm = D[0][l] + D[1][l] + D[2][l] + D[3][l] - D[8][l];
      cons += sm * sm;
    }
  };

  f32x4 P0[9], P1[9], Q0[9], Q1[9];

  // software pipeline: 36 loads in flight, counted waits, never stall-free gap
  ISSUE(P0, P1, vb);               // iter0          (out 18)
  ISSUE(Q0, Q1, vb + 8192u);       // iter1          (out 36)
  WAITV(27); consume(P0);          // iter0 group0
  WAITV(18); consume(P1);          // iter0 group1
  WAITV(9);  consume(Q0);          // iter1 group0
  WAITV(0);  consume(Q1);          // iter1 group1

  float acc[NACC];
  #pragma unroll
  for (int i = 0; i < 4; ++i)
    #pragma unroll
    for (int j = 0; j < 4; ++j) acc[i * 4 + j] = cr[i][j];
  #pragma unroll
  for (int i = 0; i < 4; ++i) { acc[16 + i] = p2[i]; acc[20 + i] = t2[i]; }
  acc[24] = cons;

  // 64-lane wave reduce
  #pragma unroll
  for (int a = 0; a < NACC; ++a) {
    #pragma unroll
    for (int off = 32; off > 0; off >>= 1)
      acc[a] += __shfl_down(acc[a], off);
  }

  __shared__ float redu[4][NACC];
  const int wave = tid >> 6, lane = tid & 63;
  if (lane == 0) {
    #pragma unroll
    for (int a = 0; a < NACC; ++a) redu[wave][a] = acc[a];
  }
  __syncthreads();
  if (tid < NACC) {
    float v = redu[0][tid] + redu[1][tid] + redu[2][tid] + redu[3][tid];
    // transposed: ws[(a*BB + b)*GX + gx] -> contiguous reads in finalize
    ws[((size_t)tid * BB + b) * GX + blockIdx.x] = v;
  }
}

__global__ __launch_bounds__(256) void floss_finalize(
    const float* __restrict__ ws, const float* __restrict__ pred_bits,
    const int* __restrict__ target_bits, const float* __restrict__ flow_loss,
    float* __restrict__ out) {
  __shared__ float sums[BB * NACC];
  const int t = threadIdx.x;

  if (t < BB * NACC) {
    const int a = t >> 3, b = t & 7;
    const float4* p = (const float4*)(ws + ((size_t)a * BB + b) * GX);
    float4 s4 = make_float4(0.f, 0.f, 0.f, 0.f);
    #pragma unroll
    for (int g = 0; g < GX / 4; ++g) {
      float4 x = p[g];
      s4.x += x.x; s4.y += x.y; s4.z += x.z; s4.w += x.w;
    }
    sums[b * NACC + a] = s4.x + s4.y + s4.z + s4.w;
  }

  float acc = 0.f;
  for (int i = t; i < NBITS; i += 256) {
    float tb = (float)target_bits[i];
    float p = pred_bits[i];
    p = fminf(fmaxf(p, 1e-7f), 1.f - 1e-7f);
    acc += tb * logf(p) + (1.f - tb) * logf(1.f - p);
  }
  #pragma unroll
  for (int off = 32; off > 0; off >>= 1) acc += __shfl_down(acc, off);
  __shared__ float sacc[4];
  const int wave = t >> 6, lane = t & 63;
  if (lane == 0) sacc[wave] = acc;
  __syncthreads();

  if (t == 0) {
    float bsum = sacc[0] + sacc[1] + sacc[2] + sacc[3];
    float bce = -bsum / (float)NBITS;
    float bit = bce * 0.5f;

    const float inv_n = 1.f / (float)CT;
    float recon_sum = 0.f;
    float cons_sum = 0.f;
    for (int b = 0; b < BB; ++b) {
      const float* w = sums + b * NACC;
      cons_sum += w[24];
      float cost[4][4];
      for (int i = 0; i < 4; ++i)
        for (int j = 0; j < 4; ++j)
          cost[i][j] = (w[16 + i] + w[20 + j] - 2.f * w[i * 4 + j]) * inv_n;
      bool used[4] = {false, false, false, false};
      for (int i = 0; i < 4; ++i) {
        int bj = 0; float bv = INFINITY;
        for (int j = 0; j < 4; ++j) {
          if (!used[j] && cost[i][j] < bv) { bv = cost[i][j]; bj = j; }
        }
        recon_sum += bv; used[bj] = true;
      }
    }
    float recon = recon_sum / (float)BB * 0.1f;
    float cons = cons_sum / (float)(BB * CT) * 0.1f;
    float flow = flow_loss[0];
    out[0] = flow;
    out[1] = recon;
    out[2] = cons;
    out[3] = bit;
    out[4] = flow + recon + cons + bit;
  }
}

extern "C" void kernel_launch(void* const* d_in, const int* in_sizes, int n_in,
                              void* d_out, int out_size, void* d_ws, size_t ws_size,
                              hipStream_t stream) {
  const float* sep       = (const float*)d_in[0];
  const float* src       = (const float*)d_in[1];
  const float* mix       = (const float*)d_in[2];
  const float* pred_bits = (const float*)d_in[3];
  const float* flow      = (const float*)d_in[4];
  const int*   tgt_bits  = (const int*)d_in[5];
  float* ws = (float*)d_ws;

  floss_reduce<<<dim3(GX, BB), TPB, 0, stream>>>(sep, src, mix, ws);
  floss_finalize<<<1, TPB, 0, stream>>>(ws, pred_bits, tgt_bits, flow, (float*)d_out);
}

// Round 8
// 41.718 us; speedup vs baseline: 1.0428x; 1.0199x over previous
//
#include <hip/hip_runtime.h>
#include <math.h>

#define BB 8
#define KK 4
#define CT 524288          // floats per (b,k) slice
#define PB (CT/4)          // 131072 float4 positions per batch stream
#define GXB 32             // blocks per batch -> 256 blocks = 1/CU
#define NT 8               // tiles per block
#define TILE 512           // float4 positions per tile
#define TPB 512            // 8 waves
#define NBITS 2048
#define NACC 25            // 16 cross + 4 p2 + 4 t2 + 1 cons

typedef float f32x4 __attribute__((ext_vector_type(4)));
typedef __attribute__((address_space(1))) const void GV;
typedef __attribute__((address_space(3))) void LV;

__device__ __forceinline__ void gl_lds16(const void* g, void* l) {
  __builtin_amdgcn_global_load_lds((GV*)g, (LV*)l, 16, 0, 0);
}

__global__ __launch_bounds__(TPB, 1) void floss_reduce(
    const float* __restrict__ sep, const float* __restrict__ src,
    const float* __restrict__ mix, float* __restrict__ ws) {
  // [buf][stream][floats]: 2 * 9 * 2048 * 4B = 144 KB
  __shared__ float smem[2][9][TILE * 4];
  __shared__ float redu[8][NACC];

  const int b = blockIdx.y;
  const int tid  = threadIdx.x;
  const int wave = tid >> 6, lane = tid & 63;

  // stream bases for this batch: waves 0-3 -> sep k, waves 4-7 -> src k
  const float* sepb = sep + (size_t)b * KK * CT;
  const float* srcb = src + (size_t)b * KK * CT;
  const float* mixb = mix + (size_t)b * CT;
  const float* mybase = (wave < 4) ? (sepb + (size_t)wave * CT)
                                   : (srcb + (size_t)(wave - 4) * CT);

  const int tile0 = blockIdx.x * NT;  // global tile index within batch

  // stage tile t into buffer c: wave w DMAs its stream's 8 KB (8 x 1KB)
  // plus 1 KB of the mix tile (slice w). 9 requests per wave.
  auto stage = [&](int t, int c) {
    const size_t pbyte = (size_t)(tile0 + t) * TILE * 16;  // byte offset of tile
    const char* gsrc = (const char*)mybase + pbyte + (size_t)lane * 16;
    float* ldst = &smem[c][wave][0];
    #pragma unroll
    for (int r = 0; r < 8; ++r)
      gl_lds16(gsrc + (size_t)r * 1024, ldst + r * 256);
    const char* gmix = (const char*)mixb + pbyte + (size_t)wave * 1024 + (size_t)lane * 16;
    gl_lds16(gmix, &smem[c][8][wave * 256]);
  };

  float cr[4][4] = {};
  float p2[4] = {};
  float t2[4] = {};
  float cons = 0.f;

  stage(0, 0);
  for (int t = 0; t < NT; ++t) {
    const int c = t & 1;
    if (t + 1 < NT) {
      stage(t + 1, c ^ 1);
      __builtin_amdgcn_sched_barrier(0);
      asm volatile("s_waitcnt vmcnt(9)" ::: "memory");  // tile t's 9 done
    } else {
      __builtin_amdgcn_sched_barrier(0);
      asm volatile("s_waitcnt vmcnt(0)" ::: "memory");
    }
    __syncthreads();                                    // all waves' tile t landed

    // compute: thread handles position p = tid of this tile
    f32x4 D[9];
    #pragma unroll
    for (int s = 0; s < 9; ++s)
      D[s] = *(const f32x4*)&smem[c][s][tid * 4];

    #pragma unroll
    for (int l = 0; l < 4; ++l) {
      #pragma unroll
      for (int i = 0; i < 4; ++i) {
        float si = D[i][l], ti = D[4 + i][l];
        p2[i] += si * si;
        t2[i] += ti * ti;
        #pragma unroll
        for (int j = 0; j < 4; ++j) cr[i][j] += si * D[4 + j][l];
      }
      float sm = D[0][l] + D[1][l] + D[2][l] + D[3][l] - D[8][l];
      cons += sm * sm;
    }
    __syncthreads();   // everyone done reading buf c before it is restaged
  }

  float acc[NACC];
  #pragma unroll
  for (int i = 0; i < 4; ++i)
    #pragma unroll
    for (int j = 0; j < 4; ++j) acc[i * 4 + j] = cr[i][j];
  #pragma unroll
  for (int i = 0; i < 4; ++i) { acc[16 + i] = p2[i]; acc[20 + i] = t2[i]; }
  acc[24] = cons;

  // 64-lane wave reduce
  #pragma unroll
  for (int a = 0; a < NACC; ++a) {
    #pragma unroll
    for (int off = 32; off > 0; off >>= 1)
      acc[a] += __shfl_down(acc[a], off);
  }
  if (lane == 0) {
    #pragma unroll
    for (int a = 0; a < NACC; ++a) redu[wave][a] = acc[a];
  }
  __syncthreads();
  if (tid < NACC) {
    float v = 0.f;
    #pragma unroll
    for (int w = 0; w < 8; ++w) v += redu[w][tid];
    // ws[(a*BB + b)*GXB + gx]
    ws[((size_t)tid * BB + b) * GXB + blockIdx.x] = v;
  }
}

__global__ __launch_bounds__(256) void floss_finalize(
    const float* __restrict__ ws, const float* __restrict__ pred_bits,
    const int* __restrict__ target_bits, const float* __restrict__ flow_loss,
    float* __restrict__ out) {
  __shared__ float sums[BB * NACC];
  const int t = threadIdx.x;

  if (t < BB * NACC) {
    const int a = t >> 3, b = t & 7;
    const float4* p = (const float4*)(ws + ((size_t)a * BB + b) * GXB);
    float4 s4 = make_float4(0.f, 0.f, 0.f, 0.f);
    #pragma unroll
    for (int g = 0; g < GXB / 4; ++g) {
      float4 x = p[g];
      s4.x += x.x; s4.y += x.y; s4.z += x.z; s4.w += x.w;
    }
    sums[b * NACC + a] = s4.x + s4.y + s4.z + s4.w;
  }

  float acc = 0.f;
  for (int i = t; i < NBITS; i += 256) {
    float tb = (float)target_bits[i];
    float p = pred_bits[i];
    p = fminf(fmaxf(p, 1e-7f), 1.f - 1e-7f);
    acc += tb * logf(p) + (1.f - tb) * logf(1.f - p);
  }
  #pragma unroll
  for (int off = 32; off > 0; off >>= 1) acc += __shfl_down(acc, off);
  __shared__ float sacc[4];
  const int wave = t >> 6, lane = t & 63;
  if (lane == 0) sacc[wave] = acc;
  __syncthreads();

  if (t == 0) {
    float bsum = sacc[0] + sacc[1] + sacc[2] + sacc[3];
    float bce = -bsum / (float)NBITS;
    float bit = bce * 0.5f;

    const float inv_n = 1.f / (float)CT;
    float recon_sum = 0.f;
    float cons_sum = 0.f;
    for (int b = 0; b < BB; ++b) {
      const float* w = sums + b * NACC;
      cons_sum += w[24];
      float cost[4][4];
      for (int i = 0; i < 4; ++i)
        for (int j = 0; j < 4; ++j)
          cost[i][j] = (w[16 + i] + w[20 + j] - 2.f * w[i * 4 + j]) * inv_n;
      bool used[4] = {false, false, false, false};
      for (int i = 0; i < 4; ++i) {
        int bj = 0; float bv = INFINITY;
        for (int j = 0; j < 4; ++j) {
          if (!used[j] && cost[i][j] < bv) { bv = cost[i][j]; bj = j; }
        }
        recon_sum += bv; used[bj] = true;
      }
    }
    float recon = recon_sum / (float)BB * 0.1f;
    float cons = cons_sum / (float)(BB * CT) * 0.1f;
    float flow = flow_loss[0];
    out[0] = flow;
    out[1] = recon;
    out[2] = cons;
    out[3] = bit;
    out[4] = flow + recon + cons + bit;
  }
}

extern "C" void kernel_launch(void* const* d_in, const int* in_sizes, int n_in,
                              void* d_out, int out_size, void* d_ws, size_t ws_size,
                              hipStream_t stream) {
  const float* sep       = (const float*)d_in[0];
  const float* src       = (const float*)d_in[1];
  const float* mix       = (const float*)d_in[2];
  const float* pred_bits = (const float*)d_in[3];
  const float* flow      = (const float*)d_in[4];
  const int*   tgt_bits  = (const int*)d_in[5];
  float* ws = (float*)d_ws;

  floss_reduce<<<dim3(GXB, BB), TPB, 0, stream>>>(sep, src, mix, ws);
  floss_finalize<<<1, 256, 0, stream>>>(ws, pred_bits, tgt_bits, flow, (float*)d_out);
}